// Round 8
// baseline (1004.382 us; speedup 1.0000x reference)
//
#include <hip/hip_runtime.h>
#include <math.h>

#define N_NODES 100000
#define N_EDGES 1600000
#define DIM 128
#define NCLS 40
#define NSHARD 8
#define SHARD_SZ (N_NODES / NSHARD)   // 12500

typedef unsigned short u16;
typedef unsigned int u32;
typedef unsigned char u8;
typedef __attribute__((ext_vector_type(8))) short bf16x8;
typedef __attribute__((ext_vector_type(4))) float f32x4;
typedef __attribute__((ext_vector_type(2))) float f32x2;

union Frag { bf16x8 v; u16 u[8]; uint4 ui; };

__device__ __forceinline__ float b2f_lo(u32 u){ union{u32 i;float f;}c; c.i=u<<16; return c.f; }
__device__ __forceinline__ float b2f_hi(u32 u){ union{u32 i;float f;}c; c.i=u&0xffff0000u; return c.f; }
__device__ __forceinline__ u16 f2b(float f){ union{float f;u32 i;}c; c.f=f; u32 r=c.i+0x7fffu+((c.i>>16)&1u); return (u16)(r>>16); }

// fp8 e4m3 (OCP) pack/unpack via HW converts
__device__ __forceinline__ u32 pack4_fp8(float a, float b, float c, float d) {
    u32 v = 0;
    v = __builtin_amdgcn_cvt_pk_fp8_f32(a, b, v, false);
    v = __builtin_amdgcn_cvt_pk_fp8_f32(c, d, v, true);
    return v;
}
__device__ __forceinline__ void addq(float* a, u32 w) {
    f32x2 p0 = __builtin_amdgcn_cvt_pk_f32_fp8(w, false);
    f32x2 p1 = __builtin_amdgcn_cvt_pk_f32_fp8(w, true);
    a[0] += p0.x; a[1] += p0.y; a[2] += p1.x; a[3] += p1.y;
}

// ---------------- CSR build ----------------

__global__ void hist2(const int* __restrict__ dA, const int* __restrict__ dB,
                      int* __restrict__ cA, int* __restrict__ cB, int E) {
    int e = blockIdx.x * blockDim.x + threadIdx.x;
    if (e < E) atomicAdd(&cA[__builtin_nontemporal_load(dA + e)], 1);
    else { e -= E; if (e < E) atomicAdd(&cB[__builtin_nontemporal_load(dB + e)], 1); }
}

__global__ void scan_blocks2(const int* __restrict__ inA, const int* __restrict__ inB,
                             int* __restrict__ outA, int* __restrict__ outB,
                             int* __restrict__ bsA, int* __restrict__ bsB,
                             int n, int nb) {
    __shared__ int s[256];
    int half = blockIdx.x >= nb, b = blockIdx.x - half * nb;
    const int* in = half ? inB : inA;
    int* out = half ? outB : outA;
    int* bs  = half ? bsB  : bsA;
    int i = b * 256 + threadIdx.x;
    int v = (i < n) ? in[i] : 0;
    s[threadIdx.x] = v;
    __syncthreads();
    for (int d = 1; d < 256; d <<= 1) {
        int t = (threadIdx.x >= d) ? s[threadIdx.x - d] : 0;
        __syncthreads();
        s[threadIdx.x] += t;
        __syncthreads();
    }
    if (i < n) out[i] = s[threadIdx.x] - v;
    if (threadIdx.x == 255) bs[b] = s[255];
}

__global__ void scan_small2(int* __restrict__ bsA, int* __restrict__ bsB, int n) {
    __shared__ int s[512];
    int* data = blockIdx.x ? bsB : bsA;
    int v = (threadIdx.x < n) ? data[threadIdx.x] : 0;
    s[threadIdx.x] = v;
    __syncthreads();
    for (int d = 1; d < 512; d <<= 1) {
        int t = (threadIdx.x >= d) ? s[threadIdx.x - d] : 0;
        __syncthreads();
        s[threadIdx.x] += t;
        __syncthreads();
    }
    if (threadIdx.x < n) data[threadIdx.x] = s[threadIdx.x] - v;
}

__global__ void add_offsets2(int* __restrict__ rsA, int* __restrict__ rsB,
                             const int* __restrict__ bsA, const int* __restrict__ bsB,
                             int n, int nb, int total) {
    int half = blockIdx.x >= nb, b = blockIdx.x - half * nb;
    int* rs = half ? rsB : rsA;
    const int* bs = half ? bsB : bsA;
    int i = b * 256 + threadIdx.x;
    if (i < n) rs[i] += bs[b];
    if (b == 0 && threadIdx.x == 0) rs[n] = total;
}

// XCD-sharded scatter with NON-TEMPORAL streaming reads: the 8x dst re-read is
// marked evict-first so it cannot displace the partially-filled dirty ss lines
// from the owning XCD's L2 (the R7 write-amplification mechanism).
__global__ void scatter_sharded(const int* __restrict__ adjA, const int* __restrict__ adjB,
        const int* __restrict__ rsA, const int* __restrict__ rsB,
        int* __restrict__ curA, int* __restrict__ curB,
        int* __restrict__ ssA, int* __restrict__ ssB,
        const int* __restrict__ perm, int E) {
    const int cls = blockIdx.x & 7;
    const int lo = cls * SHARD_SZ, hi = lo + SHARD_SZ;
    int i = (blockIdx.x >> 3) * blockDim.x + threadIdx.x;   // [0, 2E)
    if (i < E) {
        int d = __builtin_nontemporal_load(adjA + E + i);
        if (d >= lo && d < hi) {
            int p = atomicAdd(&curA[d], 1);
            ssA[rsA[d] + p] = __builtin_nontemporal_load(adjA + i);
        }
    } else {
        i -= E;
        if (i < E) {
            int d = __builtin_nontemporal_load(adjB + E + i);
            if (d >= lo && d < hi) {
                int p = atomicAdd(&curB[d], 1);
                int s = __builtin_nontemporal_load(adjB + i);
                ssB[rsB[d] + p] = perm[s];   // perm folded into branch-b sources
            }
        }
    }
}

// xb = bf16(x); xq = fp8(x); xm0 = bf16(r*x + (1-r)*x[perm])  — 4 elems/thread
__global__ void conv_mix(const float* __restrict__ x, const int* __restrict__ perm,
                         const float* __restrict__ rp, u16* __restrict__ xb,
                         u16* __restrict__ xm, u8* __restrict__ xq) {
    int i = (blockIdx.x * 256 + threadIdx.x) * 4;
    int n = i >> 7, f = i & 127;
    float r = *rp;
    int p = perm[n];
    float4 xv = *(const float4*)(x + i);
    float4 pv = *(const float4*)(x + (size_t)p * DIM + f);
    ushort4 b, m;
    b.x = f2b(xv.x); b.y = f2b(xv.y); b.z = f2b(xv.z); b.w = f2b(xv.w);
    m.x = f2b(r * xv.x + (1.f - r) * pv.x);
    m.y = f2b(r * xv.y + (1.f - r) * pv.y);
    m.z = f2b(r * xv.z + (1.f - r) * pv.z);
    m.w = f2b(r * xv.w + (1.f - r) * pv.w);
    *(ushort4*)(xb + i) = b;
    *(ushort4*)(xm + i) = m;
    *(u32*)(xq + i) = pack4_fp8(xv.x, xv.y, xv.z, xv.w);
}

// pack W fp32 -> bf16 B-fragment order, k-PERMUTED mapping:
// frag (c, t, lane l (q=l>>4, n=l&15), j) holds W[k][c*16+n],
//   k = (t>>1)*64 + q*16 + (t&1)*8 + j   (matches the 2x16B-per-edge gather layout)
__global__ void pack_weights(const float* __restrict__ Wl, const float* __restrict__ Wr,
                             u16* __restrict__ WlP, u16* __restrict__ WrP) {
    int i = blockIdx.x * 256 + threadIdx.x;          // [0, 3*16384)
    int layer = i >> 14, idx = i & 16383;
    int j = idx & 7, l = (idx >> 3) & 63, t = (idx >> 9) & 3, c = idx >> 11;
    int k = ((t >> 1) << 6) + (((l >> 4)) << 4) + ((t & 1) << 3) + j;
    int col = (c << 4) + (l & 15);
    WlP[i] = f2b(Wl[layer * 16384 + k * DIM + col]);
    WrP[i] = f2b(Wr[layer * 16384 + k * DIM + col]);
}

// ---------------- merged dual fp8 gather (2x MLP) ----------------
// Both branch streams interleaved in one predicated loop: 4 independent 16B
// loads in flight per iteration instead of 2. Per-stream summation order is
// unchanged (bit-identical results vs sequential gathers).

__device__ __forceinline__ void gather2_frags_q(const u8* __restrict__ src,
        const int* __restrict__ ssa, int ba, int ea,
        const int* __restrict__ ssb, int bb, int eb,
        int q, Frag* fA, Frag* fB) {
    float accA[32], accB[32];
    #pragma unroll
    for (int j = 0; j < 32; ++j) { accA[j] = 0.f; accB[j] = 0.f; }
    const u8* s0 = src + q * 16;
    const u8* s1 = src + 64 + q * 16;
    const int na = ea - ba, nb = eb - bb;
    int itm = na > nb ? na : nb;
    #pragma unroll
    for (int o = 32; o > 0; o >>= 1) {          // wave-max trip count
        int t = __shfl_xor(itm, o, 64);
        itm = itm > t ? itm : t;
    }
    #pragma unroll 2
    for (int i = 0; i < itm; ++i) {
        if (i < na) {
            int s = ssa[ba + i];
            uint4 v0 = *(const uint4*)(s0 + (size_t)s * DIM);
            uint4 v1 = *(const uint4*)(s1 + (size_t)s * DIM);
            addq(accA +  0, v0.x); addq(accA +  4, v0.y);
            addq(accA +  8, v0.z); addq(accA + 12, v0.w);
            addq(accA + 16, v1.x); addq(accA + 20, v1.y);
            addq(accA + 24, v1.z); addq(accA + 28, v1.w);
        }
        if (i < nb) {
            int s = ssb[bb + i];
            uint4 v0 = *(const uint4*)(s0 + (size_t)s * DIM);
            uint4 v1 = *(const uint4*)(s1 + (size_t)s * DIM);
            addq(accB +  0, v0.x); addq(accB +  4, v0.y);
            addq(accB +  8, v0.z); addq(accB + 12, v0.w);
            addq(accB + 16, v1.x); addq(accB + 20, v1.y);
            addq(accB + 24, v1.z); addq(accB + 28, v1.w);
        }
    }
    float invA = (na > 0) ? 1.f / (float)na : 0.f;
    float invB = (nb > 0) ? 1.f / (float)nb : 0.f;
    #pragma unroll
    for (int t = 0; t < 4; ++t)
        #pragma unroll
        for (int j = 0; j < 8; ++j) {
            fA[t].u[j] = f2b(accA[t * 8 + j] * invA);
            fB[t].u[j] = f2b(accB[t * 8 + j] * invB);
        }
}

// bf16 direct row (standard order) -> frags, same k-permuted slot mapping
__device__ __forceinline__ void load_frags(const u16* __restrict__ row, int q, Frag* f) {
    const u16* p = row + q * 16;
    f[0].ui = *(const uint4*)(p);
    f[1].ui = *(const uint4*)(p + 8);
    f[2].ui = *(const uint4*)(p + 64);
    f[3].ui = *(const uint4*)(p + 72);
}

// ---------------- fused sage layer: pre-pass + dual-branch main in one pass ----
// 1 wave = 16 nodes, zero LDS.
// u = Ta@Wl (shared by A_next and branch-a), s = xm@Wr:
//   A_next = relu(u + X@Wr + b)          (HAS_A)
//   xm_out = r*relu(u+s+b) + (1-r)*relu(Tb@Wl+s+b)     [pa = u+s is a free vadd]
template<bool HAS_A>
__global__ __launch_bounds__(256) void sage_layer(
        const u8* __restrict__ srcq, const u16* __restrict__ srcb,
        const u16* __restrict__ xm,
        const int* __restrict__ rs_a, const int* __restrict__ ss_a,
        const int* __restrict__ rs_b, const int* __restrict__ ss_b,
        const u16* __restrict__ WlP, const u16* __restrict__ WrP,
        const float* __restrict__ bl, const float* __restrict__ rp,
        u16* __restrict__ Aout, u8* __restrict__ Aqout, u16* __restrict__ xmout)
{
    const int lane = threadIdx.x & 63;
    const int wave = threadIdx.x >> 6;
    const int nb = blockIdx.x * 64 + wave * 16;
    const int m = lane & 15, q = lane >> 4;
    const int n = nb + m;
    const bool vld = n < N_NODES;
    const int nc = vld ? n : N_NODES - 1;

    Frag fA[4], fB[4], fX[4], fM[4];
    gather2_frags_q(srcq, ss_a, rs_a[nc], rs_a[nc + 1],
                    ss_b, rs_b[nc], rs_b[nc + 1], q, fA, fB);
    if (HAS_A) load_frags(srcb + (size_t)nc * DIM, q, fX);
    load_frags(xm + (size_t)nc * DIM, q, fM);
    float r = *rp;

    const int col = m;
    const int rowb = q * 4;
    for (int c = 0; c < 8; ++c) {
        Frag wl[4], wr[4];
        #pragma unroll
        for (int t = 0; t < 4; ++t) {
            wl[t].ui = *(const uint4*)(WlP + ((c * 4 + t) * 64 + lane) * 8);
            wr[t].ui = *(const uint4*)(WrP + ((c * 4 + t) * 64 + lane) * 8);
        }
        f32x4 u = {0.f, 0.f, 0.f, 0.f};
        #pragma unroll
        for (int t = 0; t < 4; ++t)
            u = __builtin_amdgcn_mfma_f32_16x16x32_bf16(fA[t].v, wl[t].v, u, 0, 0, 0);
        f32x4 s = {0.f, 0.f, 0.f, 0.f};
        #pragma unroll
        for (int t = 0; t < 4; ++t)
            s = __builtin_amdgcn_mfma_f32_16x16x32_bf16(fM[t].v, wr[t].v, s, 0, 0, 0);
        f32x4 pb = s;
        #pragma unroll
        for (int t = 0; t < 4; ++t)
            pb = __builtin_amdgcn_mfma_f32_16x16x32_bf16(fB[t].v, wl[t].v, pb, 0, 0, 0);
        f32x4 aA;
        if (HAS_A) {
            aA = u;
            #pragma unroll
            for (int t = 0; t < 4; ++t)
                aA = __builtin_amdgcn_mfma_f32_16x16x32_bf16(fX[t].v, wr[t].v, aA, 0, 0, 0);
        }
        f32x4 pa = u + s;
        float bias = bl[c * 16 + col];
        #pragma unroll
        for (int r2 = 0; r2 < 4; ++r2) {
            int nr = nb + rowb + r2;
            if (nr < N_NODES) {
                if (HAS_A) {
                    float v = fmaxf(aA[r2] + bias, 0.f);
                    if (Aout) Aout[(size_t)nr * DIM + c * 16 + col] = f2b(v);
                    u32 q8 = 0;
                    q8 = __builtin_amdgcn_cvt_pk_fp8_f32(v, v, q8, false);
                    Aqout[(size_t)nr * DIM + c * 16 + col] = (u8)(q8 & 0xff);
                }
                float va = fmaxf(pa[r2] + bias, 0.f);
                float vb = fmaxf(pb[r2] + bias, 0.f);
                xmout[(size_t)nr * DIM + c * 16 + col] = f2b(r * va + (1.f - r) * vb);
            }
        }
    }
}

// coalesced bf16 row -> fp32 LDS row (64 lanes x 2 feats)
__device__ __forceinline__ void load_row(const u16* __restrict__ row, int lane,
                                         float* __restrict__ ldsrow) {
    u32 v = *(const u32*)(row + lane * 2);
    ldsrow[lane * 2]     = b2f_lo(v);
    ldsrow[lane * 2 + 1] = b2f_hi(v);
}

// logits + log_softmax; 4 waves/block, one node per wave
__global__ __launch_bounds__(256) void out_kernel(const u16* __restrict__ xm,
        const float* __restrict__ Wo, const float* __restrict__ bo,
        float* __restrict__ out) {
    __shared__ float row[4][DIM];
    const int wave = threadIdx.x >> 6;
    const int lane = threadIdx.x & 63;
    const int n = blockIdx.x * 4 + wave;
    load_row(xm + (size_t)n * DIM, lane, row[wave]);
    float acc = -1e30f;
    if (lane < NCLS) {
        acc = bo[lane];
        #pragma unroll 4
        for (int k = 0; k < DIM; ++k) acc += row[wave][k] * Wo[k * NCLS + lane];
    }
    float mx = acc;
    for (int o = 32; o > 0; o >>= 1) mx = fmaxf(mx, __shfl_xor(mx, o, 64));
    float e = (lane < NCLS) ? expf(acc - mx) : 0.f;
    float sum = e;
    for (int o = 32; o > 0; o >>= 1) sum += __shfl_xor(sum, o, 64);
    if (lane < NCLS) out[(size_t)n * NCLS + lane] = acc - mx - logf(sum);
}

// ---------------- driver ----------------

extern "C" void kernel_launch(void* const* d_in, const int* in_sizes, int n_in,
                              void* d_out, int out_size, void* d_ws, size_t ws_size,
                              hipStream_t stream) {
    const float* x    = (const float*)d_in[0];
    const float* Wl   = (const float*)d_in[1];
    const float* bl   = (const float*)d_in[2];
    const float* Wr   = (const float*)d_in[3];
    const float* Wo   = (const float*)d_in[4];
    const float* bo   = (const float*)d_in[5];
    const float* rp   = (const float*)d_in[6];
    const int*   adj  = (const int*)d_in[7];
    const int*   adjb = (const int*)d_in[8];
    const int*   perm = (const int*)d_in[9];
    float* out = (float*)d_out;

    char* ws = (char*)d_ws;
    size_t off = 0;
    auto alloc = [&](size_t bytes) {
        char* p = ws + off;
        off += (bytes + 255) & ~(size_t)255;
        return p;
    };
    int* rs_a   = (int*)alloc((N_NODES + 1) * 4);
    int* rs_b   = (int*)alloc((N_NODES + 1) * 4);
    int* ss_a   = (int*)alloc((size_t)N_EDGES * 4);
    int* ss_b   = (int*)alloc((size_t)N_EDGES * 4);
    int* cur2   = (int*)alloc((size_t)2 * N_NODES * 4);   // curA | curB contiguous
    int* bsums  = (int*)alloc(1024 * 4);                  // bsA(512) | bsB(512)
    u16* WlP    = (u16*)alloc(3 * 16384 * 2);
    u16* WrP    = (u16*)alloc(3 * 16384 * 2);
    const size_t FB = (size_t)N_NODES * DIM * 2;   // bf16 feature buffer (25.6 MB)
    const size_t QB = (size_t)N_NODES * DIM;       // fp8  feature buffer (12.8 MB)
    u16* xb  = (u16*)alloc(FB);
    u16* xm0 = (u16*)alloc(FB);
    u16* A1  = (u16*)alloc(FB);
    u16* xm1 = (u16*)alloc(FB);
    u8*  xq  = (u8*)alloc(QB);
    u8*  A1q = (u8*)alloc(QB);
    // aliases (no same-kernel read/write overlap anywhere):
    u16* xm2 = xb;          // xb last read in L0; L1 writes xm2, L2 reads
    u8*  A2q = (u8*)xm0;    // xm0 last read in L0; L1 writes A2q, L2 reads
    u16* xm3 = A1;          // A1 last read in L1; L2 writes xm3, out reads
    int* curA = cur2, *curB = cur2 + N_NODES;
    int* bsA = bsums, *bsB = bsums + 512;
    // total ws use ~130 MB

    const int nbE = (N_EDGES + 255) / 256;
    const int nbN = (N_NODES + 255) / 256;   // 391

    // CSR build, both graphs per launch
    hipMemsetAsync(cur2, 0, (size_t)2 * N_NODES * 4, stream);
    hist2<<<2 * nbE, 256, 0, stream>>>(adj + N_EDGES, adjb + N_EDGES, curA, curB, N_EDGES);
    scan_blocks2<<<2 * nbN, 256, 0, stream>>>(curA, curB, rs_a, rs_b, bsA, bsB,
                                              N_NODES, nbN);
    scan_small2<<<2, 512, 0, stream>>>(bsA, bsB, nbN);
    add_offsets2<<<2 * nbN, 256, 0, stream>>>(rs_a, rs_b, bsA, bsB, N_NODES, nbN, N_EDGES);
    hipMemsetAsync(cur2, 0, (size_t)2 * N_NODES * 4, stream);
    scatter_sharded<<<NSHARD * 2 * nbE, 256, 0, stream>>>(adj, adjb, rs_a, rs_b,
        curA, curB, ss_a, ss_b, perm, N_EDGES);

    // weight packing + input conversion/mix
    pack_weights<<<192, 256, 0, stream>>>(Wl, Wr, WlP, WrP);
    conv_mix<<<(N_NODES * DIM) / 1024, 256, 0, stream>>>(x, perm, rp, xb, xm0, xq);

    const int WP = 16384;                 // packed per-layer weight stride (u16)
    const int nbS = (N_NODES + 63) / 64;  // 1563 blocks, 64 nodes each

    // fused layers (pre-pass + dual-branch main per layer)
    sage_layer<true><<<nbS, 256, 0, stream>>>(xq, xb, xm0,
        rs_a, ss_a, rs_b, ss_b, WlP, WrP, bl, rp, A1, A1q, xm1);
    sage_layer<true><<<nbS, 256, 0, stream>>>(A1q, A1, xm1,
        rs_a, ss_a, rs_b, ss_b, WlP + WP, WrP + WP, bl + DIM, rp,
        nullptr, A2q, xm2);
    sage_layer<false><<<nbS, 256, 0, stream>>>(A2q, nullptr, xm2,
        rs_a, ss_a, rs_b, ss_b, WlP + 2 * WP, WrP + 2 * WP, bl + 2 * DIM, rp,
        nullptr, nullptr, xm3);

    out_kernel<<<N_NODES / 4, 256, 0, stream>>>(xm3, Wo, bo, out);
}

// Round 9
// 745.090 us; speedup vs baseline: 1.3480x; 1.3480x over previous
//
#include <hip/hip_runtime.h>
#include <math.h>

#define N_NODES 100000
#define N_EDGES 1600000
#define DIM 128
#define NCLS 40
#define NSHARD 8
#define SHARD_SZ (N_NODES / NSHARD)   // 12500
#define CAP 64                        // bucket capacity; P(Poisson(16) >= 64) ~ 2e-18

typedef unsigned short u16;
typedef unsigned int u32;
typedef unsigned char u8;
typedef __attribute__((ext_vector_type(8))) short bf16x8;
typedef __attribute__((ext_vector_type(4))) float f32x4;
typedef __attribute__((ext_vector_type(2))) float f32x2;

union Frag { bf16x8 v; u16 u[8]; uint4 ui; };

__device__ __forceinline__ float b2f_lo(u32 u){ union{u32 i;float f;}c; c.i=u<<16; return c.f; }
__device__ __forceinline__ float b2f_hi(u32 u){ union{u32 i;float f;}c; c.i=u&0xffff0000u; return c.f; }
__device__ __forceinline__ u16 f2b(float f){ union{float f;u32 i;}c; c.f=f; u32 r=c.i+0x7fffu+((c.i>>16)&1u); return (u16)(r>>16); }

// fp8 e4m3 (OCP) pack/unpack via HW converts
__device__ __forceinline__ u32 pack4_fp8(float a, float b, float c, float d) {
    u32 v = 0;
    v = __builtin_amdgcn_cvt_pk_fp8_f32(a, b, v, false);
    v = __builtin_amdgcn_cvt_pk_fp8_f32(c, d, v, true);
    return v;
}
__device__ __forceinline__ void addq(float* a, u32 w) {
    f32x2 p0 = __builtin_amdgcn_cvt_pk_f32_fp8(w, false);
    f32x2 p1 = __builtin_amdgcn_cvt_pk_f32_fp8(w, true);
    a[0] += p0.x; a[1] += p0.y; a[2] += p1.x; a[3] += p1.y;
}

// ---------------- padded-bucket adjacency build (no hist/scan needed) ----------
// XCD-sharded: class = blockIdx&7 handles dst in [cls*12500,(cls+1)*12500), so a
// class's random 4B writes land in a ~3.2MB window that stays in the owning
// XCD's L2 until 64B lines fill (write-amp control, R7-validated). cnt[] doubles
// as the exact mean denominator (counts ALL edges, even a would-be overflow).
__global__ void scatter_pad(const int* __restrict__ adjA, const int* __restrict__ adjB,
        int* __restrict__ cntA, int* __restrict__ cntB,
        int* __restrict__ ssA, int* __restrict__ ssB,
        const int* __restrict__ perm, int E) {
    const int cls = blockIdx.x & 7;
    const int lo = cls * SHARD_SZ, hi = lo + SHARD_SZ;
    int i = (blockIdx.x >> 3) * blockDim.x + threadIdx.x;   // [0, 2E)
    if (i < E) {
        int d = adjA[E + i];
        if (d >= lo && d < hi) {
            int p = atomicAdd(&cntA[d], 1);
            if (p < CAP) ssA[d * CAP + p] = adjA[i];
        }
    } else {
        i -= E;
        if (i < E) {
            int d = adjB[E + i];
            if (d >= lo && d < hi) {
                int p = atomicAdd(&cntB[d], 1);
                if (p < CAP) ssB[d * CAP + p] = perm[adjB[i]];  // perm folded in
            }
        }
    }
}

// xb = bf16(x); xq = fp8(x); xm0 = bf16(r*x + (1-r)*x[perm])  — 4 elems/thread
__global__ void conv_mix(const float* __restrict__ x, const int* __restrict__ perm,
                         const float* __restrict__ rp, u16* __restrict__ xb,
                         u16* __restrict__ xm, u8* __restrict__ xq) {
    int i = (blockIdx.x * 256 + threadIdx.x) * 4;
    int n = i >> 7, f = i & 127;
    float r = *rp;
    int p = perm[n];
    float4 xv = *(const float4*)(x + i);
    float4 pv = *(const float4*)(x + (size_t)p * DIM + f);
    ushort4 b, m;
    b.x = f2b(xv.x); b.y = f2b(xv.y); b.z = f2b(xv.z); b.w = f2b(xv.w);
    m.x = f2b(r * xv.x + (1.f - r) * pv.x);
    m.y = f2b(r * xv.y + (1.f - r) * pv.y);
    m.z = f2b(r * xv.z + (1.f - r) * pv.z);
    m.w = f2b(r * xv.w + (1.f - r) * pv.w);
    *(ushort4*)(xb + i) = b;
    *(ushort4*)(xm + i) = m;
    *(u32*)(xq + i) = pack4_fp8(xv.x, xv.y, xv.z, xv.w);
}

// pack W fp32 -> bf16 B-fragment order, k-PERMUTED mapping:
// frag (c, t, lane l (q=l>>4, n=l&15), j) holds W[k][c*16+n],
//   k = (t>>1)*64 + q*16 + (t&1)*8 + j   (matches the 2x16B-per-edge gather layout)
__global__ void pack_weights(const float* __restrict__ Wl, const float* __restrict__ Wr,
                             u16* __restrict__ WlP, u16* __restrict__ WrP) {
    int i = blockIdx.x * 256 + threadIdx.x;          // [0, 3*16384)
    int layer = i >> 14, idx = i & 16383;
    int j = idx & 7, l = (idx >> 3) & 63, t = (idx >> 9) & 3, c = idx >> 11;
    int k = ((t >> 1) << 6) + (((l >> 4)) << 4) + ((t & 1) << 3) + j;
    int col = (c << 4) + (l & 15);
    WlP[i] = f2b(Wl[layer * 16384 + k * DIM + col]);
    WrP[i] = f2b(Wr[layer * 16384 + k * DIM + col]);
}

// ---------------- fp8 gather from padded bucket, 2x16B per edge ----------------
// (R7 sequential form — R8's merged variant regressed.) lane (m=lane&15,
// q=lane>>4): per edge 2 contiguous 16B loads; 16 nodes' streams run
// concurrently across the wave.

__device__ __forceinline__ void gather_frags_q(const u8* __restrict__ src,
        const int* __restrict__ lst, int deg, int q, Frag* f) {
    float acc[32];
    #pragma unroll
    for (int j = 0; j < 32; ++j) acc[j] = 0.f;
    const u8* s0 = src + q * 16;
    const u8* s1 = src + 64 + q * 16;
    int d = deg > CAP ? CAP : deg;
    #pragma unroll 4
    for (int e = 0; e < d; ++e) {
        int s = lst[e];
        uint4 v0 = *(const uint4*)(s0 + (size_t)s * DIM);
        uint4 v1 = *(const uint4*)(s1 + (size_t)s * DIM);
        addq(acc +  0, v0.x); addq(acc +  4, v0.y);
        addq(acc +  8, v0.z); addq(acc + 12, v0.w);
        addq(acc + 16, v1.x); addq(acc + 20, v1.y);
        addq(acc + 24, v1.z); addq(acc + 28, v1.w);
    }
    float inv = (deg > 0) ? 1.f / (float)deg : 0.f;
    #pragma unroll
    for (int t = 0; t < 4; ++t)
        #pragma unroll
        for (int j = 0; j < 8; ++j) f[t].u[j] = f2b(acc[t * 8 + j] * inv);
}

// bf16 direct row (standard order) -> frags, k-permuted slot mapping
__device__ __forceinline__ void load_frags(const u16* __restrict__ row, int q, Frag* f) {
    const u16* p = row + q * 16;
    f[0].ui = *(const uint4*)(p);
    f[1].ui = *(const uint4*)(p + 8);
    f[2].ui = *(const uint4*)(p + 64);
    f[3].ui = *(const uint4*)(p + 72);
}

// fp8 direct row -> frags (dequant to bf16), same mapping
__device__ __forceinline__ void load_frags_q8(const u8* __restrict__ row, int q, Frag* f) {
    const u8* p = row + q * 16;
    uint4 v0 = *(const uint4*)(p);
    uint4 v1 = *(const uint4*)(p + 64);
    float a[32];
    #pragma unroll
    for (int j = 0; j < 32; ++j) a[j] = 0.f;
    addq(a +  0, v0.x); addq(a +  4, v0.y); addq(a +  8, v0.z); addq(a + 12, v0.w);
    addq(a + 16, v1.x); addq(a + 20, v1.y); addq(a + 24, v1.z); addq(a + 28, v1.w);
    #pragma unroll
    for (int t = 0; t < 4; ++t)
        #pragma unroll
        for (int j = 0; j < 8; ++j) f[t].u[j] = f2b(a[t * 8 + j]);
}

// ---------------- fused sage layer: pre-pass + dual-branch main in one pass ----
// 1 wave = 16 nodes, zero LDS. u = Ta@Wl, s = xm@Wr:
//   A_next = relu(u + X@Wr + b)   (XMODE: 0=none, 1=X from bf16 srcb, 2=X from fp8 srcq)
//   xm_out = r*relu(u+s+b) + (1-r)*relu(Tb@Wl+s+b)     [pa = u+s is a free vadd]
template<int XMODE>
__global__ __launch_bounds__(256) void sage_layer(
        const u8* __restrict__ srcq, const u16* __restrict__ srcb,
        const u16* __restrict__ xm,
        const int* __restrict__ cnt_a, const int* __restrict__ ss_a,
        const int* __restrict__ cnt_b, const int* __restrict__ ss_b,
        const u16* __restrict__ WlP, const u16* __restrict__ WrP,
        const float* __restrict__ bl, const float* __restrict__ rp,
        u8* __restrict__ Aqout, u16* __restrict__ xmout)
{
    const int lane = threadIdx.x & 63;
    const int wave = threadIdx.x >> 6;
    const int nb = blockIdx.x * 64 + wave * 16;
    const int m = lane & 15, q = lane >> 4;
    const int n = nb + m;
    const bool vld = n < N_NODES;
    const int nc = vld ? n : N_NODES - 1;

    Frag fA[4], fB[4], fX[4], fM[4];
    gather_frags_q(srcq, ss_a + (size_t)nc * CAP, cnt_a[nc], q, fA);
    gather_frags_q(srcq, ss_b + (size_t)nc * CAP, cnt_b[nc], q, fB);
    if (XMODE == 1) load_frags(srcb + (size_t)nc * DIM, q, fX);
    if (XMODE == 2) load_frags_q8(srcq + (size_t)nc * DIM, q, fX);
    load_frags(xm + (size_t)nc * DIM, q, fM);
    float r = *rp;

    const int col = m;
    const int rowb = q * 4;
    for (int c = 0; c < 8; ++c) {
        Frag wl[4], wr[4];
        #pragma unroll
        for (int t = 0; t < 4; ++t) {
            wl[t].ui = *(const uint4*)(WlP + ((c * 4 + t) * 64 + lane) * 8);
            wr[t].ui = *(const uint4*)(WrP + ((c * 4 + t) * 64 + lane) * 8);
        }
        f32x4 u = {0.f, 0.f, 0.f, 0.f};
        #pragma unroll
        for (int t = 0; t < 4; ++t)
            u = __builtin_amdgcn_mfma_f32_16x16x32_bf16(fA[t].v, wl[t].v, u, 0, 0, 0);
        f32x4 s = {0.f, 0.f, 0.f, 0.f};
        #pragma unroll
        for (int t = 0; t < 4; ++t)
            s = __builtin_amdgcn_mfma_f32_16x16x32_bf16(fM[t].v, wr[t].v, s, 0, 0, 0);
        f32x4 pb = s;
        #pragma unroll
        for (int t = 0; t < 4; ++t)
            pb = __builtin_amdgcn_mfma_f32_16x16x32_bf16(fB[t].v, wl[t].v, pb, 0, 0, 0);
        f32x4 aA;
        if (XMODE != 0) {
            aA = u;
            #pragma unroll
            for (int t = 0; t < 4; ++t)
                aA = __builtin_amdgcn_mfma_f32_16x16x32_bf16(fX[t].v, wr[t].v, aA, 0, 0, 0);
        }
        f32x4 pa = u + s;
        float bias = bl[c * 16 + col];
        #pragma unroll
        for (int r2 = 0; r2 < 4; ++r2) {
            int nr = nb + rowb + r2;
            if (nr < N_NODES) {
                if (XMODE != 0) {
                    float v = fmaxf(aA[r2] + bias, 0.f);
                    u32 q8 = 0;
                    q8 = __builtin_amdgcn_cvt_pk_fp8_f32(v, v, q8, false);
                    Aqout[(size_t)nr * DIM + c * 16 + col] = (u8)(q8 & 0xff);
                }
                float va = fmaxf(pa[r2] + bias, 0.f);
                float vb = fmaxf(pb[r2] + bias, 0.f);
                xmout[(size_t)nr * DIM + c * 16 + col] = f2b(r * va + (1.f - r) * vb);
            }
        }
    }
}

// coalesced bf16 row -> fp32 LDS row (64 lanes x 2 feats)
__device__ __forceinline__ void load_row(const u16* __restrict__ row, int lane,
                                         float* __restrict__ ldsrow) {
    u32 v = *(const u32*)(row + lane * 2);
    ldsrow[lane * 2]     = b2f_lo(v);
    ldsrow[lane * 2 + 1] = b2f_hi(v);
}

// logits + log_softmax; 4 waves/block, one node per wave
__global__ __launch_bounds__(256) void out_kernel(const u16* __restrict__ xm,
        const float* __restrict__ Wo, const float* __restrict__ bo,
        float* __restrict__ out) {
    __shared__ float row[4][DIM];
    const int wave = threadIdx.x >> 6;
    const int lane = threadIdx.x & 63;
    const int n = blockIdx.x * 4 + wave;
    load_row(xm + (size_t)n * DIM, lane, row[wave]);
    float acc = -1e30f;
    if (lane < NCLS) {
        acc = bo[lane];
        #pragma unroll 4
        for (int k = 0; k < DIM; ++k) acc += row[wave][k] * Wo[k * NCLS + lane];
    }
    float mx = acc;
    for (int o = 32; o > 0; o >>= 1) mx = fmaxf(mx, __shfl_xor(mx, o, 64));
    float e = (lane < NCLS) ? expf(acc - mx) : 0.f;
    float sum = e;
    for (int o = 32; o > 0; o >>= 1) sum += __shfl_xor(sum, o, 64);
    if (lane < NCLS) out[(size_t)n * NCLS + lane] = acc - mx - logf(sum);
}

// ---------------- driver ----------------

extern "C" void kernel_launch(void* const* d_in, const int* in_sizes, int n_in,
                              void* d_out, int out_size, void* d_ws, size_t ws_size,
                              hipStream_t stream) {
    const float* x    = (const float*)d_in[0];
    const float* Wl   = (const float*)d_in[1];
    const float* bl   = (const float*)d_in[2];
    const float* Wr   = (const float*)d_in[3];
    const float* Wo   = (const float*)d_in[4];
    const float* bo   = (const float*)d_in[5];
    const float* rp   = (const float*)d_in[6];
    const int*   adj  = (const int*)d_in[7];
    const int*   adjb = (const int*)d_in[8];
    const int*   perm = (const int*)d_in[9];
    float* out = (float*)d_out;

    char* ws = (char*)d_ws;
    size_t off = 0;
    auto alloc = [&](size_t bytes) {
        char* p = ws + off;
        off += (bytes + 255) & ~(size_t)255;
        return p;
    };
    int* cur2   = (int*)alloc((size_t)2 * N_NODES * 4);       // cntA | cntB (0.8 MB)
    int* ss_a   = (int*)alloc((size_t)N_NODES * CAP * 4);     // 25.6 MB padded buckets
    int* ss_b   = (int*)alloc((size_t)N_NODES * CAP * 4);     // 25.6 MB
    u16* WlP    = (u16*)alloc(3 * 16384 * 2);
    u16* WrP    = (u16*)alloc(3 * 16384 * 2);
    const size_t FB = (size_t)N_NODES * DIM * 2;   // bf16 feature buffer (25.6 MB)
    const size_t QB = (size_t)N_NODES * DIM;       // fp8  feature buffer (12.8 MB)
    u16* xb  = (u16*)alloc(FB);
    u16* xm0 = (u16*)alloc(FB);
    u16* xm1 = (u16*)alloc(FB);
    u8*  xq  = (u8*)alloc(QB);
    u8*  A1q = (u8*)alloc(QB);
    // aliases (no same-kernel read/write overlap anywhere):
    u16* xm2 = xb;          // xb read only in L0; L1 writes xm2, L2 reads
    u8*  A2q = (u8*)xm0;    // xm0 read only in L0; L1 writes A2q, L2 reads
    u16* xm3 = xm1;         // xm1 read only in L1; L2 writes xm3, out reads
    int* cntA = cur2, *cntB = cur2 + N_NODES;
    // total ws use ~155 MB

    const int nbE = (N_EDGES + 255) / 256;   // 6250

    // padded-bucket adjacency build (replaces hist/scan/CSR: 14 -> 8 dispatches)
    hipMemsetAsync(cur2, 0, (size_t)2 * N_NODES * 4, stream);
    scatter_pad<<<NSHARD * 2 * nbE, 256, 0, stream>>>(adj, adjb, cntA, cntB,
                                                      ss_a, ss_b, perm, N_EDGES);

    // weight packing + input conversion/mix
    pack_weights<<<192, 256, 0, stream>>>(Wl, Wr, WlP, WrP);
    conv_mix<<<(N_NODES * DIM) / 1024, 256, 0, stream>>>(x, perm, rp, xb, xm0, xq);

    const int WP = 16384;                 // packed per-layer weight stride (u16)
    const int nbS = (N_NODES + 63) / 64;  // 1563 blocks, 64 nodes each

    // fused layers (pre-pass + dual-branch main per layer)
    sage_layer<1><<<nbS, 256, 0, stream>>>(xq, xb, xm0,
        cntA, ss_a, cntB, ss_b, WlP, WrP, bl, rp, A1q, xm1);
    sage_layer<2><<<nbS, 256, 0, stream>>>(A1q, nullptr, xm1,
        cntA, ss_a, cntB, ss_b, WlP + WP, WrP + WP, bl + DIM, rp, A2q, xm2);
    sage_layer<0><<<nbS, 256, 0, stream>>>(A2q, nullptr, xm2,
        cntA, ss_a, cntB, ss_b, WlP + 2 * WP, WrP + 2 * WP, bl + 2 * DIM, rp,
        nullptr, xm3);

    out_kernel<<<N_NODES / 4, 256, 0, stream>>>(xm3, Wo, bo, out);
}